// Round 1
// baseline (177.005 us; speedup 1.0000x reference)
//
#include <hip/hip_runtime.h>

// Cost volume: out[b,h,w,dy*9+dx] = leaky_relu( mean_c( prv[b,h,w,c] * nxt[b,h+dy-4,w+dx-4,c] ), 0.1 )
// prv, nxt: (8,128,128,192) f32, NHWC contiguous. nxt zero-padded outside bounds.

#define B_   8
#define H_   128
#define W_   128
#define C_   192
#define R_   4
#define ND   9        // 2R+1
#define NDISP 81      // ND*ND
#define TILE 16
#define HALO 24       // TILE + 2R
#define KC   8        // channels per LDS chunk
#define PST  12       // floats per pixel slot in LDS (8 data + 4 pad -> 48B stride, bank-friendly)

__global__ __launch_bounds__(256, 2)
void cost_volume_kernel(const float* __restrict__ prv,
                        const float* __restrict__ nxt,
                        float* __restrict__ out) {
    __shared__ float s_nxt[HALO * HALO * PST];   // 24*24*12 = 6912 floats = 27.6 KB

    const int tx = threadIdx.x & 15;
    const int ty = threadIdx.x >> 4;
    const int w0 = blockIdx.x * TILE;
    const int h0 = blockIdx.y * TILE;
    const int b  = blockIdx.z;

    float acc[NDISP];
#pragma unroll
    for (int i = 0; i < NDISP; ++i) acc[i] = 0.f;

    const float* prv_pix = prv + (((size_t)(b * H_ + (h0 + ty)) * W_) + (w0 + tx)) * C_;

    for (int c0 = 0; c0 < C_; c0 += KC) {
        if (c0) __syncthreads();   // protect LDS from previous iteration's readers

        // stage nxt halo tile (24x24 pixels x KC channels), zero-pad out of range
        for (int idx = threadIdx.x; idx < HALO * HALO; idx += 256) {
            const int py = idx / HALO;
            const int px = idx - py * HALO;
            const int gh = h0 + py - R_;
            const int gw = w0 + px - R_;
            float4 a = make_float4(0.f, 0.f, 0.f, 0.f);
            float4 c = a;
            if ((unsigned)gh < (unsigned)H_ && (unsigned)gw < (unsigned)W_) {
                const float* g = nxt + (((size_t)(b * H_ + gh) * W_) + gw) * C_ + c0;
                a = *(const float4*)(g);
                c = *(const float4*)(g + 4);
            }
            float* s = s_nxt + idx * PST;
            *(float4*)(s)     = a;
            *(float4*)(s + 4) = c;
        }
        __syncthreads();

        // prv pixel channels straight to registers (private to this thread)
        float p[KC];
        {
            const float4 a = *(const float4*)(prv_pix + c0);
            const float4 c = *(const float4*)(prv_pix + c0 + 4);
            p[0] = a.x; p[1] = a.y; p[2] = a.z; p[3] = a.w;
            p[4] = c.x; p[5] = c.y; p[6] = c.z; p[7] = c.w;
        }

        const float* srow = s_nxt + (ty * HALO + tx) * PST;
#pragma unroll
        for (int dy = 0; dy < ND; ++dy) {
#pragma unroll
            for (int dx = 0; dx < ND; ++dx) {
                const float* s = srow + (dy * HALO + dx) * PST;
                const float4 a = *(const float4*)(s);
                const float4 c = *(const float4*)(s + 4);
                float sum = acc[dy * ND + dx];
                sum += p[0] * a.x + p[1] * a.y + p[2] * a.z + p[3] * a.w;
                sum += p[4] * c.x + p[5] * c.y + p[6] * c.z + p[7] * c.w;
                acc[dy * ND + dx] = sum;
            }
        }
    }

    // epilogue: mean + leaky relu, 81 consecutive floats per pixel
    const float inv = 1.0f / (float)C_;
    float* o = out + (((size_t)(b * H_ + (h0 + ty)) * W_) + (w0 + tx)) * NDISP;
#pragma unroll
    for (int i = 0; i < NDISP; ++i) {
        const float v = acc[i] * inv;
        o[i] = v >= 0.f ? v : 0.1f * v;
    }
}

extern "C" void kernel_launch(void* const* d_in, const int* in_sizes, int n_in,
                              void* d_out, int out_size, void* d_ws, size_t ws_size,
                              hipStream_t stream) {
    const float* prv = (const float*)d_in[0];
    const float* nxt = (const float*)d_in[1];
    float* out = (float*)d_out;

    dim3 grid(W_ / TILE, H_ / TILE, B_);   // (8, 8, 8) = 512 blocks
    cost_volume_kernel<<<grid, 256, 0, stream>>>(prv, nxt, out);
}

// Round 2
// 101.192 us; speedup vs baseline: 1.7492x; 1.7492x over previous
//
#include <hip/hip_runtime.h>

// out[b,h,w,dy*9+dx] = leaky_relu( mean_c( prv[b,h,w,c] * nxt[b,h+dy-4,w+dx-4,c] ), 0.1 )
// Banded bf16 MFMA formulation: per (b,h,dy), S[w,w'] = sum_c prv[w,c]*nxt[w',c], |w'-w|<=4.
// Per 16-wide w-tile, two 16x16x32 MFMAs with B col-tiles at w'-offsets -4 and +12 cover the band.

#define B_ 8
#define H_ 128
#define W_ 128
#define C_ 192
#define ND 9
#define NDISP 81
#define HT 8            // output rows per block (one per wave)
#define WT 32           // output cols per block
#define KS 32           // channels per k-step
#define NK 6            // 192/32
#define BROWS (HT + 8)  // 16 nxt rows staged
#define BCOLS (WT + 8)  // 40 nxt cols staged
#define ACH (4 * HT * WT)        // 1024 16B-chunks of A per kstep
#define BCH (4 * BROWS * BCOLS)  // 2560 16B-chunks of B per kstep

typedef short short8 __attribute__((ext_vector_type(8)));
typedef float f32x4 __attribute__((ext_vector_type(4)));

static __device__ __forceinline__ unsigned short f2bf(float f) {
    unsigned u = __float_as_uint(f);
    u += 0x7FFFu + ((u >> 16) & 1u);   // round-to-nearest-even
    return (unsigned short)(u >> 16);
}

static __device__ __forceinline__ short8 cvt8(float4 x, float4 y) {
    short8 v;
    v[0] = (short)f2bf(x.x); v[1] = (short)f2bf(x.y);
    v[2] = (short)f2bf(x.z); v[3] = (short)f2bf(x.w);
    v[4] = (short)f2bf(y.x); v[5] = (short)f2bf(y.y);
    v[6] = (short)f2bf(y.z); v[7] = (short)f2bf(y.w);
    return v;
}

__global__ __launch_bounds__(512, 2)
void cv_mfma(const float* __restrict__ prv, const float* __restrict__ nxt,
             float* __restrict__ out) {
    // LDS layout: [c-chunk 0..3][pixel][8 bf16]; a wave's frag read (16 lanes per
    // c-chunk, consecutive pixels) is a contiguous 256B run per quarter -> conflict-free.
    __shared__ short8 sA[ACH];   // 16 KB
    __shared__ short8 sB[BCH];   // 40 KB

    const int tid = threadIdx.x;
    const int w0 = blockIdx.x * WT;
    const int h0 = blockIdx.y * HT;
    const int b  = blockIdx.z;

    const int lane = tid & 63;
    const int wid  = tid >> 6;    // 0..7: this wave's output row (h0+wid)
    const int lq = lane & 15;
    const int lc = lane >> 4;

    f32x4 acc[ND][4];
#pragma unroll
    for (int d = 0; d < ND; ++d)
#pragma unroll
        for (int t = 0; t < 4; ++t)
            acc[d][t] = (f32x4){0.f, 0.f, 0.f, 0.f};

    for (int ks = 0; ks < NK; ++ks) {
        if (ks) __syncthreads();

        // ---- stage A: prv[h0+r][w0+p][ks*32 + c*8 .. +7]  (always in range)
#pragma unroll
        for (int it = 0; it < ACH / 512; ++it) {
            const int idx = tid + it * 512;
            const int c = idx >> 8;            // / (HT*WT)
            const int r = (idx >> 5) & (HT - 1);
            const int p = idx & (WT - 1);
            const float* g = prv + ((size_t)((b * H_ + h0 + r) * W_ + w0 + p)) * C_ + ks * KS + c * 8;
            const float4 x = *(const float4*)g;
            const float4 y = *(const float4*)(g + 4);
            sA[idx] = cvt8(x, y);
        }
        // ---- stage B: nxt[h0-4+r][w0-4+pp][...] with zero padding
#pragma unroll
        for (int it = 0; it < BCH / 512; ++it) {
            const int idx = tid + it * 512;
            const int c = idx / (BROWS * BCOLS);
            const int rem = idx - c * (BROWS * BCOLS);
            const int r = rem / BCOLS;
            const int pp = rem - r * BCOLS;
            const int gh = h0 - 4 + r;
            const int gw = w0 - 4 + pp;
            short8 v = (short8){0, 0, 0, 0, 0, 0, 0, 0};
            if ((unsigned)gh < (unsigned)H_ && (unsigned)gw < (unsigned)W_) {
                const float* g = nxt + ((size_t)((b * H_ + gh) * W_ + gw)) * C_ + ks * KS + c * 8;
                const float4 x = *(const float4*)g;
                const float4 y = *(const float4*)(g + 4);
                v = cvt8(x, y);
            }
            sB[idx] = v;
        }
        __syncthreads();

        // ---- compute: wave `wid` does row h0+wid, all 9 dy, 2 w-tiles x 2 col-tiles
        const short8 a0 = sA[(lc * HT + wid) * WT + lq];        // w-tile 0
        const short8 a1 = sA[(lc * HT + wid) * WT + 16 + lq];   // w-tile 1
#pragma unroll
        for (int dy = 0; dy < ND; ++dy) {
            const int rr = wid + dy;                            // nxt row in sB
            const int base = (lc * BROWS + rr) * BCOLS + lq;
            const short8 b0 = sB[base];        // cols w0-4+q
            const short8 b1 = sB[base + 16];   // cols w0+12+q
            const short8 b2 = sB[base + 32];   // cols w0+28+q
            acc[dy][0] = __builtin_amdgcn_mfma_f32_16x16x32_bf16(a0, b0, acc[dy][0], 0, 0, 0);
            acc[dy][1] = __builtin_amdgcn_mfma_f32_16x16x32_bf16(a0, b1, acc[dy][1], 0, 0, 0);
            acc[dy][2] = __builtin_amdgcn_mfma_f32_16x16x32_bf16(a1, b1, acc[dy][2], 0, 0, 0);
            acc[dy][3] = __builtin_amdgcn_mfma_f32_16x16x32_bf16(a1, b2, acc[dy][3], 0, 0, 0);
        }
    }

    // ---- epilogue: D layout col=lane&15, row=4*(lane>>4)+reg (verified m89/m91)
    // tile pair at offsets -4 / +12: dx = q - r (first) or q - r + 16 (second); exclusive.
    const float inv = 1.0f / (float)C_;
    const int h = h0 + wid;
#pragma unroll
    for (int wt = 0; wt < 2; ++wt) {
#pragma unroll
        for (int rg = 0; rg < 4; ++rg) {
            const int r = 4 * lc + rg;
            const int w = w0 + 16 * wt + r;
            float* o = out + ((size_t)((b * H_ + h) * W_ + w)) * NDISP;
            const int dxa = lq - r;
            const int dxb = dxa + 16;
            if (dxa >= 0 && dxa <= 8) {
#pragma unroll
                for (int dy = 0; dy < ND; ++dy) {
                    const float v = acc[dy][2 * wt][rg] * inv;
                    o[dy * ND + dxa] = v >= 0.f ? v : 0.1f * v;
                }
            }
            if (dxb <= 8) {   // dxb >= 1 always
#pragma unroll
                for (int dy = 0; dy < ND; ++dy) {
                    const float v = acc[dy][2 * wt + 1][rg] * inv;
                    o[dy * ND + dxb] = v >= 0.f ? v : 0.1f * v;
                }
            }
        }
    }
}

extern "C" void kernel_launch(void* const* d_in, const int* in_sizes, int n_in,
                              void* d_out, int out_size, void* d_ws, size_t ws_size,
                              hipStream_t stream) {
    const float* prv = (const float*)d_in[0];
    const float* nxt = (const float*)d_in[1];
    float* out = (float*)d_out;

    dim3 grid(W_ / WT, H_ / HT, B_);   // (4, 16, 8) = 512 blocks
    cv_mfma<<<grid, 512, 0, stream>>>(prv, nxt, out);
}